// Round 1
// baseline (162.249 us; speedup 1.0000x reference)
//
#include <hip/hip_runtime.h>
#include <hip/hip_bf16.h>

typedef __attribute__((ext_vector_type(4))) float f32x4;
typedef __attribute__((ext_vector_type(8))) short bf16x8;

#define NROWS 32768
#define DIM   2048
#define NEXP  64

__device__ __forceinline__ short f2bf(float f) {
    __hip_bfloat16 h = __float2bfloat16(f);   // RTNE
    short s;
    __builtin_memcpy(&s, &h, 2);
    return s;
}

// ---------------- Kernel A: expert prep -------------------------------------
// Writes: ekbf [64][2048] bf16 (row-major), ekT [2048][64] bf16, enorm[64] f32.
__global__ __launch_bounds__(256) void prep_experts(
    const float* __restrict__ ek,
    short* __restrict__ ekbf,
    short* __restrict__ ekT,
    float* __restrict__ enorm)
{
    const int e = blockIdx.x;      // expert 0..63
    const int t = threadIdx.x;     // 0..255
    const float* row = ek + e * DIM;
    float ss = 0.f;
#pragma unroll
    for (int i = 0; i < 2; ++i) {
        const int c4 = t + i * 256;              // float4 index 0..511
        const float4 v = ((const float4*)row)[c4];
        ss += v.x * v.x + v.y * v.y + v.z * v.z + v.w * v.w;
        short4 b;
        b.x = f2bf(v.x); b.y = f2bf(v.y); b.z = f2bf(v.z); b.w = f2bf(v.w);
        *(short4*)(ekbf + e * DIM + c4 * 4) = b;
        const int d = c4 * 4;
        ekT[(d + 0) * NEXP + e] = b.x;
        ekT[(d + 1) * NEXP + e] = b.y;
        ekT[(d + 2) * NEXP + e] = b.z;
        ekT[(d + 3) * NEXP + e] = b.w;
    }
    // block reduction of sum-of-squares
#pragma unroll
    for (int s = 1; s < 64; s <<= 1) ss += __shfl_xor(ss, s);
    __shared__ float red[4];
    if ((t & 63) == 0) red[t >> 6] = ss;
    __syncthreads();
    if (t == 0) enorm[e] = sqrtf(red[0] + red[1] + red[2] + red[3]);
}

// ---------------- Main kernel ------------------------------------------------
// 64 rows per block, 4 waves (1 m-tile each for dots; 1 d-slice each for PV).
__global__ __launch_bounds__(256) void cosmoe_main(
    const float* __restrict__ z,
    const short* __restrict__ ekbf,   // [64][2048] bf16
    const short* __restrict__ ekT,    // [2048][64] bf16
    const float* __restrict__ enorm,  // [64] f32
    float* __restrict__ out_sim,      // [32768][64] f32
    float* __restrict__ out_wei)      // [32768][2048] f32
{
    const int tid = threadIdx.x;
    const int w   = tid >> 6;     // wave 0..3
    const int l   = tid & 63;
    const int lr  = l & 15;       // A-row / B-col / C-col within 16-tile
    const int lg  = l >> 4;       // k-group 0..3
    const int base_row = blockIdx.x * 64;

    // ---- Phase 1: dots = z @ ek^T for 64 rows; f32 z-norms on the side.
    // A-frag: lane holds z[w*16+lr][kk*32 + lg*8 + j], j=0..7 (f32->bf16).
    // B-frag: lane holds ek[nt*16+lr][kk*32 + lg*8 + j]  (contiguous 16B).
    const float* zrow = z + (size_t)(base_row + w * 16 + lr) * DIM + lg * 8;
    f32x4 acc[4];
#pragma unroll
    for (int nt = 0; nt < 4; ++nt) acc[nt] = f32x4{0.f, 0.f, 0.f, 0.f};
    float ssq = 0.f;

    for (int kk = 0; kk < DIM / 32; ++kk) {
        const float4 a0 = *(const float4*)(zrow + kk * 32);
        const float4 a1 = *(const float4*)(zrow + kk * 32 + 4);
        ssq += a0.x * a0.x + a0.y * a0.y + a0.z * a0.z + a0.w * a0.w
             + a1.x * a1.x + a1.y * a1.y + a1.z * a1.z + a1.w * a1.w;
        bf16x8 af;
        af[0] = f2bf(a0.x); af[1] = f2bf(a0.y); af[2] = f2bf(a0.z); af[3] = f2bf(a0.w);
        af[4] = f2bf(a1.x); af[5] = f2bf(a1.y); af[6] = f2bf(a1.z); af[7] = f2bf(a1.w);
        const int koff = kk * 32 + lg * 8;
#pragma unroll
        for (int nt = 0; nt < 4; ++nt) {
            const bf16x8 bf = *(const bf16x8*)(ekbf + (nt * 16 + lr) * DIM + koff);
            acc[nt] = __builtin_amdgcn_mfma_f32_16x16x32_bf16(af, bf, acc[nt], 0, 0, 0);
        }
    }
    // row (w*16+lr) sumsq is split across the 4 k-groups (lanes l^16, l^32):
    ssq += __shfl_xor(ssq, 16);
    ssq += __shfl_xor(ssq, 32);
    const float zn_mine = sqrtf(ssq);   // ||z[w*16+lr]||, held by lanes {lr,lr+16,..}

    // ---- Phase 2: similarity + softmax over 64 experts.
    // C layout (verified m89): lane holds D[lg*4+j][lr] per n-tile.
    float zn_j[4];
#pragma unroll
    for (int j = 0; j < 4; ++j) zn_j[j] = __shfl(zn_mine, lg * 4 + j);
    float en_nt[4];
#pragma unroll
    for (int nt = 0; nt < 4; ++nt) en_nt[nt] = enorm[nt * 16 + lr];

    float sim[4][4];   // [nt][j]
#pragma unroll
    for (int j = 0; j < 4; ++j)
#pragma unroll
        for (int nt = 0; nt < 4; ++nt)
            sim[nt][j] = acc[nt][j] / fmaxf(zn_j[j] * en_nt[nt], 1e-8f);

    // write similarity
#pragma unroll
    for (int j = 0; j < 4; ++j) {
        const size_t ro = (size_t)(base_row + w * 16 + lg * 4 + j) * NEXP + lr;
#pragma unroll
        for (int nt = 0; nt < 4; ++nt) out_sim[ro + nt * 16] = sim[nt][j];
    }

    // softmax along e: 4 local values + 16-lane butterfly
    float wgt[4][4];
#pragma unroll
    for (int j = 0; j < 4; ++j) {
        float mx = fmaxf(fmaxf(sim[0][j], sim[1][j]), fmaxf(sim[2][j], sim[3][j]));
#pragma unroll
        for (int s = 1; s < 16; s <<= 1) mx = fmaxf(mx, __shfl_xor(mx, s));
        float sum = 0.f;
#pragma unroll
        for (int nt = 0; nt < 4; ++nt) { wgt[nt][j] = __expf(sim[nt][j] - mx); sum += wgt[nt][j]; }
#pragma unroll
        for (int s = 1; s < 16; s <<= 1) sum += __shfl_xor(sum, s);
        const float inv = 1.0f / sum;
#pragma unroll
        for (int nt = 0; nt < 4; ++nt) wgt[nt][j] *= inv;
    }

    // re-layout W: C-frag -> A-frag via small padded LDS tile (stride 72 => 2-way max)
    __shared__ __align__(16) short Wl[4][16][72];
#pragma unroll
    for (int j = 0; j < 4; ++j)
#pragma unroll
        for (int nt = 0; nt < 4; ++nt)
            Wl[w][lg * 4 + j][nt * 16 + lr] = f2bf(wgt[nt][j]);
    __syncthreads();

    // ---- Phase 3: weighted = W[64x64] @ ek[64x2048]; wave w owns d-slice [w*512, w*512+512)
    bf16x8 afr[4][2];
#pragma unroll
    for (int mt = 0; mt < 4; ++mt)
#pragma unroll
        for (int ks = 0; ks < 2; ++ks)
            afr[mt][ks] = *(const bf16x8*)&Wl[mt][lr][ks * 32 + lg * 8];

    for (int ntl = 0; ntl < 32; ++ntl) {
        const int d0 = w * 512 + ntl * 16;
        const short* bp = ekT + (size_t)(d0 + lr) * NEXP + lg * 8;
        const bf16x8 b0 = *(const bf16x8*)bp;          // experts 0..31 slice
        const bf16x8 b1 = *(const bf16x8*)(bp + 32);   // experts 32..63 slice
        f32x4 oacc[4];
#pragma unroll
        for (int mt = 0; mt < 4; ++mt) {
            oacc[mt] = f32x4{0.f, 0.f, 0.f, 0.f};
            oacc[mt] = __builtin_amdgcn_mfma_f32_16x16x32_bf16(afr[mt][0], b0, oacc[mt], 0, 0, 0);
            oacc[mt] = __builtin_amdgcn_mfma_f32_16x16x32_bf16(afr[mt][1], b1, oacc[mt], 0, 0, 0);
        }
#pragma unroll
        for (int mt = 0; mt < 4; ++mt)
#pragma unroll
            for (int j = 0; j < 4; ++j)
                out_wei[(size_t)(base_row + mt * 16 + lg * 4 + j) * DIM + d0 + lr] = oacc[mt][j];
    }
}

// ---------------- launch -----------------------------------------------------
extern "C" void kernel_launch(void* const* d_in, const int* in_sizes, int n_in,
                              void* d_out, int out_size, void* d_ws, size_t ws_size,
                              hipStream_t stream) {
    const float* z  = (const float*)d_in[0];
    const float* ek = (const float*)d_in[1];
    float* out_sim = (float*)d_out;
    float* out_wei = out_sim + (size_t)NROWS * NEXP;

    short* ekbf  = (short*)d_ws;                 // 64*2048*2   = 256 KiB
    short* ekT   = ekbf + NEXP * DIM;            // 2048*64*2   = 256 KiB
    float* enorm = (float*)(ekT + DIM * NEXP);   // 64*4 bytes

    prep_experts<<<NEXP, 256, 0, stream>>>(ek, ekbf, ekT, enorm);
    cosmoe_main<<<NROWS / 64, 256, 0, stream>>>(z, ekbf, ekT, enorm, out_sim, out_wei);
}